// Round 12
// baseline (56.406 us; speedup 1.0000x reference)
//
#include <hip/hip_runtime.h>
#include <hip/hip_fp16.h>
#include <math.h>

#define BB 64
#define TT 1024
#define DD 256
#define BT (BB*TT)
#define SS 16            // token-chunks per batch
#define TPC (TT/SS)      // 64 tokens per chunk

typedef float v4f __attribute__((ext_vector_type(4)));
typedef unsigned short v4h __attribute__((ext_vector_type(4)));

// ---- workspace layout (in floats) ----
#define PA_OFF   0                       // [1024][256] chunk token sums (kA->kB1)
#define CENT_OFF (PA_OFF + 1024*DD)      // [64][256] per-batch centroids (kB1->kC)
#define MEAN_OFF (CENT_OFF + BB*DD)      // [256] final mean (kC blk0 -> kE)
#define SC_OFF   (MEAN_OFF + DD)         // scalars: [1]=invden, [2]=mb, [3]=ww, [4]=mean0
#define SCAL_OFF (SC_OFF + 16)           // [BT][4] per-token (xy, by, y0, 0)
#define DP_OFF   (SCAL_OFF + BT*4)       // [1024] dist^2 partial sums
#define XH_OFF   (DP_OFF + 1024)         // [BT*64] v4h fp16 copy of x
#define WS_BYTES_NEEDED ((size_t)(XH_OFF)*4 + (size_t)BT*64*8)

__device__ __forceinline__ float block_reduce_256(float v) {
    __shared__ float sh[4];
    #pragma unroll
    for (int o = 32; o; o >>= 1) v += __shfl_xor(v, o, 64);
    int lane = threadIdx.x & 63, w = threadIdx.x >> 6;
    if (lane == 0) sh[w] = v;
    __syncthreads();
    float r = sh[0] + sh[1] + sh[2] + sh[3];
    __syncthreads();
    return r;
}

__device__ __forceinline__ v4h f4toh4(float4 v) {
    v4h r;
    r.x = __half_as_ushort(__float2half(v.x));
    r.y = __half_as_ushort(__float2half(v.y));
    r.z = __half_as_ushort(__float2half(v.z));
    r.w = __half_as_ushort(__float2half(v.w));
    return r;
}
__device__ __forceinline__ float4 h4tof4(v4h h) {
    float4 r;
    r.x = __half2float(__ushort_as_half(h.x));
    r.y = __half2float(__ushort_as_half(h.y));
    r.z = __half2float(__ushort_as_half(h.z));
    r.w = __half2float(__ushort_as_half(h.w));
    return r;
}

// ---- Kernel A (fp16 path): token sums + fp16 copy (NT loads of dead-after x) ----
__global__ void kA_h(const float* __restrict__ x, float* __restrict__ ws,
                     v4h* __restrict__ xh) {
    int tid = threadIdx.x, lane = tid & 63, wv = tid >> 6;
    int chunk = blockIdx.x;                       // 0..1023
    int tok0 = chunk * 64 + wv * 16;
    const v4f* xp = (const v4f*)x + (size_t)tok0 * 64 + lane;
    v4h* hp = xh + (size_t)tok0 * 64 + lane;
    float4 s = {0.f, 0.f, 0.f, 0.f};
    #pragma unroll
    for (int t = 0; t < 16; ++t) {
        v4f vv = __builtin_nontemporal_load(xp + (size_t)t * 64);
        float4 v; v.x = vv.x; v.y = vv.y; v.z = vv.z; v.w = vv.w;
        s.x += v.x; s.y += v.y; s.z += v.z; s.w += v.w;
        hp[(size_t)t * 64] = f4toh4(v);
    }
    __shared__ float4 sh4[4][64];
    sh4[wv][lane] = s;
    __syncthreads();
    if (wv == 0) {
        float4 a = sh4[0][lane], b = sh4[1][lane], c = sh4[2][lane], d = sh4[3][lane];
        a.x += b.x + c.x + d.x;
        a.y += b.y + c.y + d.y;
        a.z += b.z + c.z + d.z;
        a.w += b.w + c.w + d.w;
        ((float4*)(ws + PA_OFF + (size_t)chunk * DD))[lane] = a;
    }
}

// ---- Kernel A (f32 fallback) ----
__global__ void kA_f(const float* __restrict__ x, float* __restrict__ ws) {
    int tid = threadIdx.x, lane = tid & 63, wv = tid >> 6;
    int chunk = blockIdx.x;
    int tok0 = chunk * 64 + wv * 16;
    const float4* xp = (const float4*)x + (size_t)tok0 * 64 + lane;
    float4 s = {0.f, 0.f, 0.f, 0.f};
    #pragma unroll
    for (int t = 0; t < 16; ++t) {
        float4 v = xp[(size_t)t * 64];
        s.x += v.x; s.y += v.y; s.z += v.z; s.w += v.w;
    }
    __shared__ float4 sh4[4][64];
    sh4[wv][lane] = s;
    __syncthreads();
    if (wv == 0) {
        float4 a = sh4[0][lane], b = sh4[1][lane], c = sh4[2][lane], d = sh4[3][lane];
        a.x += b.x + c.x + d.x;
        a.y += b.y + c.y + d.y;
        a.z += b.z + c.z + d.z;
        a.w += b.w + c.w + d.w;
        ((float4*)(ws + PA_OFF + (size_t)chunk * DD))[lane] = a;
    }
}

// ---- Kernel B1: per-batch centroid (grid = 64) ----
__global__ void kB1(float* __restrict__ ws) {
    int b = blockIdx.x, d = threadIdx.x;
    float m = 0.f;
    #pragma unroll
    for (int s = 0; s < SS; ++s) m += ws[PA_OFF + (size_t)(b*SS + s) * DD + d];
    m *= (1.0f / TT);
    float dot = block_reduce_256(d == 0 ? -m*m : m*m);
    ws[CENT_OFF + (size_t)b * DD + d] = m / sqrtf(fmaxf(-dot, 1e-8f));
}

// ---- shared prologue: fold centroids -> mean (identical order in every block) ----
__device__ __forceinline__ float mean_prologue(const float* __restrict__ ws,
                                               const float* __restrict__ beta,
                                               float* smean, float* ssc) {
    int tid = threadIdx.x;
    float a = 0.f;
    #pragma unroll 8
    for (int b = 0; b < BB; ++b) a += ws[CENT_OFF + (size_t)b * DD + tid];
    a *= (1.0f / BB);
    float dot = block_reduce_256(tid == 0 ? -a * a : a * a);
    float mean_d = a / sqrtf(fmaxf(-dot, 1e-8f));
    smean[tid] = mean_d;
    float bt = beta[tid];
    float w_d = mean_d + bt;
    float mb  = block_reduce_256(tid == 0 ? -mean_d * bt : mean_d * bt);
    float wwp = block_reduce_256(tid == 0 ? -w_d * w_d : w_d * w_d);
    if (tid == 0) {
        ssc[0] = 1.0f / (1.0f - mb);
        ssc[1] = mb;
        ssc[2] = wwp;
        ssc[3] = mean_d;     // mean0 (tid 0 owns dim 0)
    }
    __syncthreads();
    return mean_d;
}

// ---- Kernel C (fp16): mean prologue + 16-lane-group dots + d^2 partials ----
__global__ void kC_h(const v4h* __restrict__ xh, const float* __restrict__ beta,
                     float* __restrict__ ws) {
    int tid = threadIdx.x, lane = tid & 63, wv = tid >> 6;
    int g  = lane >> 4;
    int gl = lane & 15;

    __shared__ float smean[DD];
    __shared__ float ssc[4];
    float mean_d = mean_prologue(ws, beta, smean, ssc);

    if (blockIdx.x == 0) {      // publish for kE
        ws[MEAN_OFF + tid] = mean_d;
        if (tid < 4) ws[SC_OFF + 1 + tid] = ssc[tid];
    }

    float4 mc[4], bc[4];
    #pragma unroll
    for (int c = 0; c < 4; ++c) {
        mc[c] = ((const float4*)smean)[c * 16 + gl];
        bc[c] = ((const float4*)beta)[c * 16 + gl];
    }

    float lsum = 0.f;
    int tbase = blockIdx.x * 64 + wv * 16;
    #pragma unroll
    for (int it = 0; it < 4; ++it) {
        int tok = tbase + it * 4 + g;
        const v4h* xq = xh + (size_t)tok * 64 + gl;
        float4 q0 = h4tof4(xq[0]),  q1 = h4tof4(xq[16]),
               q2 = h4tof4(xq[32]), q3 = h4tof4(xq[48]);

        float pxy = mc[0].x*q0.x + mc[0].y*q0.y + mc[0].z*q0.z + mc[0].w*q0.w
                  + mc[1].x*q1.x + mc[1].y*q1.y + mc[1].z*q1.z + mc[1].w*q1.w
                  + mc[2].x*q2.x + mc[2].y*q2.y + mc[2].z*q2.z + mc[2].w*q2.w
                  + mc[3].x*q3.x + mc[3].y*q3.y + mc[3].z*q3.z + mc[3].w*q3.w;
        float pby = bc[0].x*q0.x + bc[0].y*q0.y + bc[0].z*q0.z + bc[0].w*q0.w
                  + bc[1].x*q1.x + bc[1].y*q1.y + bc[1].z*q1.z + bc[1].w*q1.w
                  + bc[2].x*q2.x + bc[2].y*q2.y + bc[2].z*q2.z + bc[2].w*q2.w
                  + bc[3].x*q3.x + bc[3].y*q3.y + bc[3].z*q3.z + bc[3].w*q3.w;
        if (gl == 0) {
            pxy -= 2.0f * mc[0].x * q0.x;
            pby -= 2.0f * bc[0].x * q0.x;
        }
        #pragma unroll
        for (int o = 1; o < 16; o <<= 1) {
            pxy += __shfl_xor(pxy, o, 64);
            pby += __shfl_xor(pby, o, 64);
        }
        if (gl == 0) {
            float4 sc; sc.x = pxy; sc.y = pby; sc.z = q0.x; sc.w = 0.f;
            ((float4*)(ws + SCAL_OFF))[tok] = sc;
            float d = acoshf(fmaxf(-pxy, 1.0f + 1e-7f));
            lsum += fmaxf(d * d, 1e-8f);
        }
    }
    float tot = block_reduce_256(lsum);
    if (tid == 0) ws[DP_OFF + blockIdx.x] = tot;
}

// ---- Kernel C (f32 fallback) ----
__global__ void kC_f(const float* __restrict__ x, const float* __restrict__ beta,
                     float* __restrict__ ws) {
    int tid = threadIdx.x, lane = tid & 63, wv = tid >> 6;
    int g  = lane >> 4;
    int gl = lane & 15;

    __shared__ float smean[DD];
    __shared__ float ssc[4];
    float mean_d = mean_prologue(ws, beta, smean, ssc);
    if (blockIdx.x == 0) {
        ws[MEAN_OFF + tid] = mean_d;
        if (tid < 4) ws[SC_OFF + 1 + tid] = ssc[tid];
    }

    float4 mc[4], bc[4];
    #pragma unroll
    for (int c = 0; c < 4; ++c) {
        mc[c] = ((const float4*)smean)[c * 16 + gl];
        bc[c] = ((const float4*)beta)[c * 16 + gl];
    }
    float lsum = 0.f;
    int tbase = blockIdx.x * 64 + wv * 16;
    #pragma unroll
    for (int it = 0; it < 4; ++it) {
        int tok = tbase + it * 4 + g;
        const float4* xq = (const float4*)(x + (size_t)tok * DD) + gl;
        float4 q0 = xq[0], q1 = xq[16], q2 = xq[32], q3 = xq[48];
        float pxy = mc[0].x*q0.x + mc[0].y*q0.y + mc[0].z*q0.z + mc[0].w*q0.w
                  + mc[1].x*q1.x + mc[1].y*q1.y + mc[1].z*q1.z + mc[1].w*q1.w
                  + mc[2].x*q2.x + mc[2].y*q2.y + mc[2].z*q2.z + mc[2].w*q2.w
                  + mc[3].x*q3.x + mc[3].y*q3.y + mc[3].z*q3.z + mc[3].w*q3.w;
        float pby = bc[0].x*q0.x + bc[0].y*q0.y + bc[0].z*q0.z + bc[0].w*q0.w
                  + bc[1].x*q1.x + bc[1].y*q1.y + bc[1].z*q1.z + bc[1].w*q1.w
                  + bc[2].x*q2.x + bc[2].y*q2.y + bc[2].z*q2.z + bc[2].w*q2.w
                  + bc[3].x*q3.x + bc[3].y*q3.y + bc[3].z*q3.z + bc[3].w*q3.w;
        if (gl == 0) {
            pxy -= 2.0f * mc[0].x * q0.x;
            pby -= 2.0f * bc[0].x * q0.x;
        }
        #pragma unroll
        for (int o = 1; o < 16; o <<= 1) {
            pxy += __shfl_xor(pxy, o, 64);
            pby += __shfl_xor(pby, o, 64);
        }
        if (gl == 0) {
            float4 sc; sc.x = pxy; sc.y = pby; sc.z = q0.x; sc.w = 0.f;
            ((float4*)(ws + SCAL_OFF))[tok] = sc;
            float d = acoshf(fmaxf(-pxy, 1.0f + 1e-7f));
            lsum += fmaxf(d * d, 1e-8f);
        }
    }
    float tot = block_reduce_256(lsum);
    if (tid == 0) ws[DP_OFF + blockIdx.x] = tot;
}

// ---- ABC epilogue helper (shared math) ----
__device__ __forceinline__ float4 abc_from_scal(float4 sc, float scale,
                                                float invden, float mb,
                                                float ww, float mean0) {
    float xy = sc.x, by = sc.y, y0 = sc.z;
    float d   = acoshf(fmaxf(-xy, 1.0f + 1e-7f));
    float un2 = fmaxf(xy * xy - 1.0f, 1e-8f);
    float f1  = d * scale / sqrtf(un2);
    float u0  = y0 + xy * mean0;
    float en2 = f1 * f1 * (un2 + 2.0f * u0 * u0);
    float n   = sqrtf(en2);
    float factor = fminf(1.0f, 32.0f / fmaxf(n, 1e-8f));
    float ff1 = factor * f1;
    float bv  = ff1 * (by + xy * mb);
    float coeff = bv * invden;
    float vn2 = ff1 * ff1 * un2 + 2.0f * coeff * bv + coeff * coeff * ww;
    float vn  = sqrtf(fmaxf(vn2, 1e-8f));
    float shv = sinhf(vn) / vn;
    float chv = coshf(vn);
    float4 abc;
    abc.x = shv * ff1;
    abc.y = shv * (ff1 * xy + coeff);
    abc.z = chv + shv * coeff;
    abc.w = 0.f;
    return abc;
}

// ---- Kernel E (fp16): var fold + thread-per-token ABC + stream (NT in, NT out) ----
__global__ void kE_h(const v4h* __restrict__ xh, const float* __restrict__ beta,
                     const float* __restrict__ gamma,
                     const float* __restrict__ ws, float* __restrict__ out) {
    int tid = threadIdx.x, lane = tid & 63, wv = tid >> 6;
    int tok0 = blockIdx.x * 64;

    // deterministic var fold (identical order in every block)
    float s = 0.f;
    #pragma unroll
    for (int i = tid; i < 1024; i += 256) s += ws[DP_OFF + i];
    float tot = block_reduce_256(s);
    float var = sqrtf(tot / (float)BT);
    float scale = gamma[0] / (var + 1e-5f);

    __shared__ float4 sabc[64];
    if (tid < 64) {
        float4 sc = ((const float4*)(ws + SCAL_OFF))[tok0 + tid];
        sabc[tid] = abc_from_scal(sc, scale, ws[SC_OFF + 1], ws[SC_OFF + 2],
                                  ws[SC_OFF + 3], ws[SC_OFF + 4]);
    }
    __syncthreads();

    float4 m4 = ((const float4*)(ws + MEAN_OFF))[lane];
    float4 b4 = ((const float4*)beta)[lane];
    const v4h* xp = xh + (size_t)(tok0 + wv * 16) * 64 + lane;
    v4f* op = (v4f*)out + (size_t)(tok0 + wv * 16) * 64 + lane;

    #pragma unroll 4
    for (int t = 0; t < 16; ++t) {
        float4 abc = sabc[wv * 16 + t];
        float A = abc.x, B = abc.y, C = abc.z;
        float4 v = h4tof4(__builtin_nontemporal_load(xp + (size_t)t * 64));
        v4f o4;
        o4.x = A * v.x + B * m4.x + C * b4.x;
        o4.y = A * v.y + B * m4.y + C * b4.y;
        o4.z = A * v.z + B * m4.z + C * b4.z;
        o4.w = A * v.w + B * m4.w + C * b4.w;
        __builtin_nontemporal_store(o4, op + (size_t)t * 64);
    }
}

// ---- Kernel E (f32 fallback) ----
__global__ void kE_f(const float* __restrict__ x, const float* __restrict__ beta,
                     const float* __restrict__ gamma,
                     const float* __restrict__ ws, float* __restrict__ out) {
    int tid = threadIdx.x, lane = tid & 63, wv = tid >> 6;
    int tok0 = blockIdx.x * 64;

    float s = 0.f;
    #pragma unroll
    for (int i = tid; i < 1024; i += 256) s += ws[DP_OFF + i];
    float tot = block_reduce_256(s);
    float var = sqrtf(tot / (float)BT);
    float scale = gamma[0] / (var + 1e-5f);

    __shared__ float4 sabc[64];
    if (tid < 64) {
        float4 sc = ((const float4*)(ws + SCAL_OFF))[tok0 + tid];
        sabc[tid] = abc_from_scal(sc, scale, ws[SC_OFF + 1], ws[SC_OFF + 2],
                                  ws[SC_OFF + 3], ws[SC_OFF + 4]);
    }
    __syncthreads();

    float4 m4 = ((const float4*)(ws + MEAN_OFF))[lane];
    float4 b4 = ((const float4*)beta)[lane];
    const float4* xp = (const float4*)x + (size_t)(tok0 + wv * 16) * 64 + lane;
    v4f* op = (v4f*)out + (size_t)(tok0 + wv * 16) * 64 + lane;

    #pragma unroll 4
    for (int t = 0; t < 16; ++t) {
        float4 abc = sabc[wv * 16 + t];
        float A = abc.x, B = abc.y, C = abc.z;
        float4 v = xp[(size_t)t * 64];
        v4f o4;
        o4.x = A * v.x + B * m4.x + C * b4.x;
        o4.y = A * v.y + B * m4.y + C * b4.y;
        o4.z = A * v.z + B * m4.z + C * b4.z;
        o4.w = A * v.w + B * m4.w + C * b4.w;
        __builtin_nontemporal_store(o4, op + (size_t)t * 64);
    }
}

extern "C" void kernel_launch(void* const* d_in, const int* in_sizes, int n_in,
                              void* d_out, int out_size, void* d_ws, size_t ws_size,
                              hipStream_t stream) {
    const float* x     = (const float*)d_in[0];
    const float* beta  = (const float*)d_in[1];
    const float* gamma = (const float*)d_in[2];
    float* out = (float*)d_out;
    float* ws  = (float*)d_ws;

    if (ws_size >= WS_BYTES_NEEDED) {
        v4h* xh = (v4h*)(ws + XH_OFF);
        kA_h<<<1024,  256, 0, stream>>>(x, ws, xh);
        kB1 <<<64,    256, 0, stream>>>(ws);
        kC_h<<<1024,  256, 0, stream>>>(xh, beta, ws);
        kE_h<<<BT/64, 256, 0, stream>>>(xh, beta, gamma, ws, out);
    } else {
        kA_f<<<1024,  256, 0, stream>>>(x, ws);
        kB1 <<<64,    256, 0, stream>>>(ws);
        kC_f<<<1024,  256, 0, stream>>>(x, beta, ws);
        kE_f<<<BT/64, 256, 0, stream>>>(x, beta, gamma, ws, out);
    }
}

// Round 13
// 53.486 us; speedup vs baseline: 1.0546x; 1.0546x over previous
//
#include <hip/hip_runtime.h>
#include <hip/hip_fp16.h>
#include <math.h>

#define BB 64
#define TT 1024
#define DD 256
#define BT (BB*TT)
#define SS 16            // token-chunks per batch
#define TPC (TT/SS)      // 64 tokens per chunk

typedef float v4f __attribute__((ext_vector_type(4)));
typedef unsigned short v4h __attribute__((ext_vector_type(4)));

// ---- workspace layout (in floats) ----
#define PA_OFF   0                       // [1024][256] chunk token sums (kA->kB1)
#define CENT_OFF (PA_OFF + 1024*DD)      // [64][256] per-batch centroids (kB1->kC)
#define MEAN_OFF (CENT_OFF + BB*DD)      // [256] final mean (kC blk0 -> kE)
#define SC_OFF   (MEAN_OFF + DD)         // scalars: [1]=invden, [2]=mb, [3]=ww, [4]=mean0
#define SCAL_OFF (SC_OFF + 16)           // [BT][4] per-token (xy, by, y0, 0)
#define DP_OFF   (SCAL_OFF + BT*4)       // [1024] dist^2 partial sums
#define XH_OFF   (DP_OFF + 1024)         // [BT*64] v4h fp16 copy of x
#define WS_BYTES_NEEDED ((size_t)(XH_OFF)*4 + (size_t)BT*64*8)

__device__ __forceinline__ float block_reduce_256(float v) {
    __shared__ float sh[4];
    #pragma unroll
    for (int o = 32; o; o >>= 1) v += __shfl_xor(v, o, 64);
    int lane = threadIdx.x & 63, w = threadIdx.x >> 6;
    if (lane == 0) sh[w] = v;
    __syncthreads();
    float r = sh[0] + sh[1] + sh[2] + sh[3];
    __syncthreads();
    return r;
}

__device__ __forceinline__ v4h f4toh4(float4 v) {
    v4h r;
    r.x = __half_as_ushort(__float2half(v.x));
    r.y = __half_as_ushort(__float2half(v.y));
    r.z = __half_as_ushort(__float2half(v.z));
    r.w = __half_as_ushort(__float2half(v.w));
    return r;
}
__device__ __forceinline__ float4 h4tof4(v4h h) {
    float4 r;
    r.x = __half2float(__ushort_as_half(h.x));
    r.y = __half2float(__ushort_as_half(h.y));
    r.z = __half2float(__ushort_as_half(h.z));
    r.w = __half2float(__ushort_as_half(h.w));
    return r;
}

// ---- Kernel A (fp16 path): token sums + fp16 copy ----
__global__ void kA_h(const float* __restrict__ x, float* __restrict__ ws,
                     v4h* __restrict__ xh) {
    int tid = threadIdx.x, lane = tid & 63, wv = tid >> 6;
    int chunk = blockIdx.x;                       // 0..1023
    int tok0 = chunk * 64 + wv * 16;
    const float4* xp = (const float4*)x + (size_t)tok0 * 64 + lane;
    v4h* hp = xh + (size_t)tok0 * 64 + lane;
    float4 s = {0.f, 0.f, 0.f, 0.f};
    #pragma unroll
    for (int t = 0; t < 16; ++t) {
        float4 v = xp[(size_t)t * 64];
        s.x += v.x; s.y += v.y; s.z += v.z; s.w += v.w;
        hp[(size_t)t * 64] = f4toh4(v);
    }
    __shared__ float4 sh4[4][64];
    sh4[wv][lane] = s;
    __syncthreads();
    if (wv == 0) {
        float4 a = sh4[0][lane], b = sh4[1][lane], c = sh4[2][lane], d = sh4[3][lane];
        a.x += b.x + c.x + d.x;
        a.y += b.y + c.y + d.y;
        a.z += b.z + c.z + d.z;
        a.w += b.w + c.w + d.w;
        ((float4*)(ws + PA_OFF + (size_t)chunk * DD))[lane] = a;
    }
}

// ---- Kernel A (f32 fallback) ----
__global__ void kA_f(const float* __restrict__ x, float* __restrict__ ws) {
    int tid = threadIdx.x, lane = tid & 63, wv = tid >> 6;
    int chunk = blockIdx.x;
    int tok0 = chunk * 64 + wv * 16;
    const float4* xp = (const float4*)x + (size_t)tok0 * 64 + lane;
    float4 s = {0.f, 0.f, 0.f, 0.f};
    #pragma unroll
    for (int t = 0; t < 16; ++t) {
        float4 v = xp[(size_t)t * 64];
        s.x += v.x; s.y += v.y; s.z += v.z; s.w += v.w;
    }
    __shared__ float4 sh4[4][64];
    sh4[wv][lane] = s;
    __syncthreads();
    if (wv == 0) {
        float4 a = sh4[0][lane], b = sh4[1][lane], c = sh4[2][lane], d = sh4[3][lane];
        a.x += b.x + c.x + d.x;
        a.y += b.y + c.y + d.y;
        a.z += b.z + c.z + d.z;
        a.w += b.w + c.w + d.w;
        ((float4*)(ws + PA_OFF + (size_t)chunk * DD))[lane] = a;
    }
}

// ---- Kernel B1: per-batch centroid (grid = 64) ----
__global__ void kB1(float* __restrict__ ws) {
    int b = blockIdx.x, d = threadIdx.x;
    float m = 0.f;
    #pragma unroll
    for (int s = 0; s < SS; ++s) m += ws[PA_OFF + (size_t)(b*SS + s) * DD + d];
    m *= (1.0f / TT);
    float dot = block_reduce_256(d == 0 ? -m*m : m*m);
    ws[CENT_OFF + (size_t)b * DD + d] = m / sqrtf(fmaxf(-dot, 1e-8f));
}

// ---- shared prologue: fold centroids -> mean (identical order in every block) ----
__device__ __forceinline__ float mean_prologue(const float* __restrict__ ws,
                                               const float* __restrict__ beta,
                                               float* smean, float* ssc) {
    int tid = threadIdx.x;
    float a = 0.f;
    #pragma unroll 8
    for (int b = 0; b < BB; ++b) a += ws[CENT_OFF + (size_t)b * DD + tid];
    a *= (1.0f / BB);
    float dot = block_reduce_256(tid == 0 ? -a * a : a * a);
    float mean_d = a / sqrtf(fmaxf(-dot, 1e-8f));
    smean[tid] = mean_d;
    float bt = beta[tid];
    float w_d = mean_d + bt;
    float mb  = block_reduce_256(tid == 0 ? -mean_d * bt : mean_d * bt);
    float wwp = block_reduce_256(tid == 0 ? -w_d * w_d : w_d * w_d);
    if (tid == 0) {
        ssc[0] = 1.0f / (1.0f - mb);
        ssc[1] = mb;
        ssc[2] = wwp;
        ssc[3] = mean_d;     // mean0 (tid 0 owns dim 0)
    }
    __syncthreads();
    return mean_d;
}

// ---- Kernel C (fp16): mean prologue + 16-lane-group dots + d^2 partials ----
__global__ void kC_h(const v4h* __restrict__ xh, const float* __restrict__ beta,
                     float* __restrict__ ws) {
    int tid = threadIdx.x, lane = tid & 63, wv = tid >> 6;
    int g  = lane >> 4;
    int gl = lane & 15;

    __shared__ float smean[DD];
    __shared__ float ssc[4];
    float mean_d = mean_prologue(ws, beta, smean, ssc);

    if (blockIdx.x == 0) {      // publish for kE
        ws[MEAN_OFF + tid] = mean_d;
        if (tid < 4) ws[SC_OFF + 1 + tid] = ssc[tid];
    }

    float4 mc[4], bc[4];
    #pragma unroll
    for (int c = 0; c < 4; ++c) {
        mc[c] = ((const float4*)smean)[c * 16 + gl];
        bc[c] = ((const float4*)beta)[c * 16 + gl];
    }

    float lsum = 0.f;
    int tbase = blockIdx.x * 64 + wv * 16;
    #pragma unroll
    for (int it = 0; it < 4; ++it) {
        int tok = tbase + it * 4 + g;
        const v4h* xq = xh + (size_t)tok * 64 + gl;
        float4 q0 = h4tof4(xq[0]),  q1 = h4tof4(xq[16]),
               q2 = h4tof4(xq[32]), q3 = h4tof4(xq[48]);

        float pxy = mc[0].x*q0.x + mc[0].y*q0.y + mc[0].z*q0.z + mc[0].w*q0.w
                  + mc[1].x*q1.x + mc[1].y*q1.y + mc[1].z*q1.z + mc[1].w*q1.w
                  + mc[2].x*q2.x + mc[2].y*q2.y + mc[2].z*q2.z + mc[2].w*q2.w
                  + mc[3].x*q3.x + mc[3].y*q3.y + mc[3].z*q3.z + mc[3].w*q3.w;
        float pby = bc[0].x*q0.x + bc[0].y*q0.y + bc[0].z*q0.z + bc[0].w*q0.w
                  + bc[1].x*q1.x + bc[1].y*q1.y + bc[1].z*q1.z + bc[1].w*q1.w
                  + bc[2].x*q2.x + bc[2].y*q2.y + bc[2].z*q2.z + bc[2].w*q2.w
                  + bc[3].x*q3.x + bc[3].y*q3.y + bc[3].z*q3.z + bc[3].w*q3.w;
        if (gl == 0) {
            pxy -= 2.0f * mc[0].x * q0.x;
            pby -= 2.0f * bc[0].x * q0.x;
        }
        #pragma unroll
        for (int o = 1; o < 16; o <<= 1) {
            pxy += __shfl_xor(pxy, o, 64);
            pby += __shfl_xor(pby, o, 64);
        }
        if (gl == 0) {
            float4 sc; sc.x = pxy; sc.y = pby; sc.z = q0.x; sc.w = 0.f;
            ((float4*)(ws + SCAL_OFF))[tok] = sc;
            float d = acoshf(fmaxf(-pxy, 1.0f + 1e-7f));
            lsum += fmaxf(d * d, 1e-8f);
        }
    }
    float tot = block_reduce_256(lsum);
    if (tid == 0) ws[DP_OFF + blockIdx.x] = tot;
}

// ---- Kernel C (f32 fallback) ----
__global__ void kC_f(const float* __restrict__ x, const float* __restrict__ beta,
                     float* __restrict__ ws) {
    int tid = threadIdx.x, lane = tid & 63, wv = tid >> 6;
    int g  = lane >> 4;
    int gl = lane & 15;

    __shared__ float smean[DD];
    __shared__ float ssc[4];
    float mean_d = mean_prologue(ws, beta, smean, ssc);
    if (blockIdx.x == 0) {
        ws[MEAN_OFF + tid] = mean_d;
        if (tid < 4) ws[SC_OFF + 1 + tid] = ssc[tid];
    }

    float4 mc[4], bc[4];
    #pragma unroll
    for (int c = 0; c < 4; ++c) {
        mc[c] = ((const float4*)smean)[c * 16 + gl];
        bc[c] = ((const float4*)beta)[c * 16 + gl];
    }
    float lsum = 0.f;
    int tbase = blockIdx.x * 64 + wv * 16;
    #pragma unroll
    for (int it = 0; it < 4; ++it) {
        int tok = tbase + it * 4 + g;
        const float4* xq = (const float4*)(x + (size_t)tok * DD) + gl;
        float4 q0 = xq[0], q1 = xq[16], q2 = xq[32], q3 = xq[48];
        float pxy = mc[0].x*q0.x + mc[0].y*q0.y + mc[0].z*q0.z + mc[0].w*q0.w
                  + mc[1].x*q1.x + mc[1].y*q1.y + mc[1].z*q1.z + mc[1].w*q1.w
                  + mc[2].x*q2.x + mc[2].y*q2.y + mc[2].z*q2.z + mc[2].w*q2.w
                  + mc[3].x*q3.x + mc[3].y*q3.y + mc[3].z*q3.z + mc[3].w*q3.w;
        float pby = bc[0].x*q0.x + bc[0].y*q0.y + bc[0].z*q0.z + bc[0].w*q0.w
                  + bc[1].x*q1.x + bc[1].y*q1.y + bc[1].z*q1.z + bc[1].w*q1.w
                  + bc[2].x*q2.x + bc[2].y*q2.y + bc[2].z*q2.z + bc[2].w*q2.w
                  + bc[3].x*q3.x + bc[3].y*q3.y + bc[3].z*q3.z + bc[3].w*q3.w;
        if (gl == 0) {
            pxy -= 2.0f * mc[0].x * q0.x;
            pby -= 2.0f * bc[0].x * q0.x;
        }
        #pragma unroll
        for (int o = 1; o < 16; o <<= 1) {
            pxy += __shfl_xor(pxy, o, 64);
            pby += __shfl_xor(pby, o, 64);
        }
        if (gl == 0) {
            float4 sc; sc.x = pxy; sc.y = pby; sc.z = q0.x; sc.w = 0.f;
            ((float4*)(ws + SCAL_OFF))[tok] = sc;
            float d = acoshf(fmaxf(-pxy, 1.0f + 1e-7f));
            lsum += fmaxf(d * d, 1e-8f);
        }
    }
    float tot = block_reduce_256(lsum);
    if (tid == 0) ws[DP_OFF + blockIdx.x] = tot;
}

// ---- ABC epilogue helper (shared math) ----
__device__ __forceinline__ float4 abc_from_scal(float4 sc, float scale,
                                                float invden, float mb,
                                                float ww, float mean0) {
    float xy = sc.x, by = sc.y, y0 = sc.z;
    float d   = acoshf(fmaxf(-xy, 1.0f + 1e-7f));
    float un2 = fmaxf(xy * xy - 1.0f, 1e-8f);
    float f1  = d * scale / sqrtf(un2);
    float u0  = y0 + xy * mean0;
    float en2 = f1 * f1 * (un2 + 2.0f * u0 * u0);
    float n   = sqrtf(en2);
    float factor = fminf(1.0f, 32.0f / fmaxf(n, 1e-8f));
    float ff1 = factor * f1;
    float bv  = ff1 * (by + xy * mb);
    float coeff = bv * invden;
    float vn2 = ff1 * ff1 * un2 + 2.0f * coeff * bv + coeff * coeff * ww;
    float vn  = sqrtf(fmaxf(vn2, 1e-8f));
    float shv = sinhf(vn) / vn;
    float chv = coshf(vn);
    float4 abc;
    abc.x = shv * ff1;
    abc.y = shv * (ff1 * xy + coeff);
    abc.z = chv + shv * coeff;
    abc.w = 0.f;
    return abc;
}

// ---- Kernel E (fp16): var fold + thread-per-token ABC + stream (NT store only) ----
__global__ void kE_h(const v4h* __restrict__ xh, const float* __restrict__ beta,
                     const float* __restrict__ gamma,
                     const float* __restrict__ ws, float* __restrict__ out) {
    int tid = threadIdx.x, lane = tid & 63, wv = tid >> 6;
    int tok0 = blockIdx.x * 64;

    // deterministic var fold (identical order in every block)
    float s = 0.f;
    #pragma unroll
    for (int i = tid; i < 1024; i += 256) s += ws[DP_OFF + i];
    float tot = block_reduce_256(s);
    float var = sqrtf(tot / (float)BT);
    float scale = gamma[0] / (var + 1e-5f);

    __shared__ float4 sabc[64];
    if (tid < 64) {
        float4 sc = ((const float4*)(ws + SCAL_OFF))[tok0 + tid];
        sabc[tid] = abc_from_scal(sc, scale, ws[SC_OFF + 1], ws[SC_OFF + 2],
                                  ws[SC_OFF + 3], ws[SC_OFF + 4]);
    }
    __syncthreads();

    float4 m4 = ((const float4*)(ws + MEAN_OFF))[lane];
    float4 b4 = ((const float4*)beta)[lane];
    const v4h* xp = xh + (size_t)(tok0 + wv * 16) * 64 + lane;
    v4f* op = (v4f*)out + (size_t)(tok0 + wv * 16) * 64 + lane;

    #pragma unroll 4
    for (int t = 0; t < 16; ++t) {
        float4 abc = sabc[wv * 16 + t];
        float A = abc.x, B = abc.y, C = abc.z;
        float4 v = h4tof4(xp[(size_t)t * 64]);
        v4f o4;
        o4.x = A * v.x + B * m4.x + C * b4.x;
        o4.y = A * v.y + B * m4.y + C * b4.y;
        o4.z = A * v.z + B * m4.z + C * b4.z;
        o4.w = A * v.w + B * m4.w + C * b4.w;
        __builtin_nontemporal_store(o4, op + (size_t)t * 64);
    }
}

// ---- Kernel E (f32 fallback) ----
__global__ void kE_f(const float* __restrict__ x, const float* __restrict__ beta,
                     const float* __restrict__ gamma,
                     const float* __restrict__ ws, float* __restrict__ out) {
    int tid = threadIdx.x, lane = tid & 63, wv = tid >> 6;
    int tok0 = blockIdx.x * 64;

    float s = 0.f;
    #pragma unroll
    for (int i = tid; i < 1024; i += 256) s += ws[DP_OFF + i];
    float tot = block_reduce_256(s);
    float var = sqrtf(tot / (float)BT);
    float scale = gamma[0] / (var + 1e-5f);

    __shared__ float4 sabc[64];
    if (tid < 64) {
        float4 sc = ((const float4*)(ws + SCAL_OFF))[tok0 + tid];
        sabc[tid] = abc_from_scal(sc, scale, ws[SC_OFF + 1], ws[SC_OFF + 2],
                                  ws[SC_OFF + 3], ws[SC_OFF + 4]);
    }
    __syncthreads();

    float4 m4 = ((const float4*)(ws + MEAN_OFF))[lane];
    float4 b4 = ((const float4*)beta)[lane];
    const float4* xp = (const float4*)x + (size_t)(tok0 + wv * 16) * 64 + lane;
    v4f* op = (v4f*)out + (size_t)(tok0 + wv * 16) * 64 + lane;

    #pragma unroll 4
    for (int t = 0; t < 16; ++t) {
        float4 abc = sabc[wv * 16 + t];
        float A = abc.x, B = abc.y, C = abc.z;
        float4 v = xp[(size_t)t * 64];
        v4f o4;
        o4.x = A * v.x + B * m4.x + C * b4.x;
        o4.y = A * v.y + B * m4.y + C * b4.y;
        o4.z = A * v.z + B * m4.z + C * b4.z;
        o4.w = A * v.w + B * m4.w + C * b4.w;
        __builtin_nontemporal_store(o4, op + (size_t)t * 64);
    }
}

extern "C" void kernel_launch(void* const* d_in, const int* in_sizes, int n_in,
                              void* d_out, int out_size, void* d_ws, size_t ws_size,
                              hipStream_t stream) {
    const float* x     = (const float*)d_in[0];
    const float* beta  = (const float*)d_in[1];
    const float* gamma = (const float*)d_in[2];
    float* out = (float*)d_out;
    float* ws  = (float*)d_ws;

    if (ws_size >= WS_BYTES_NEEDED) {
        v4h* xh = (v4h*)(ws + XH_OFF);
        kA_h<<<1024,  256, 0, stream>>>(x, ws, xh);
        kB1 <<<64,    256, 0, stream>>>(ws);
        kC_h<<<1024,  256, 0, stream>>>(xh, beta, ws);
        kE_h<<<BT/64, 256, 0, stream>>>(xh, beta, gamma, ws, out);
    } else {
        kA_f<<<1024,  256, 0, stream>>>(x, ws);
        kB1 <<<64,    256, 0, stream>>>(ws);
        kC_f<<<1024,  256, 0, stream>>>(x, beta, ws);
        kE_f<<<BT/64, 256, 0, stream>>>(x, beta, gamma, ws, out);
    }
}